// Round 5
// baseline (122.390 us; speedup 1.0000x reference)
//
#include <hip/hip_runtime.h>
#include <hip/hip_fp16.h>

// Problem constants
#define N_VISITS  16384
#define MAX_CODES 64
#define DIM       64
#define NUM_CODES 100000
#define NRANGES   2
#define RANGE_SIZE 50000   // 2 * 50000 = 100000 exactly

typedef float f32x4 __attribute__((ext_vector_type(4)));
typedef float f32x2 __attribute__((ext_vector_type(2)));

// ---------------------------------------------------------------------------
// Kernel A: convert emb table fp32 -> fp16 (12.8 MB). Exact grid: 3125 x 256
// threads = 800000 16B->8B conversions, one per thread, no loop.
// ---------------------------------------------------------------------------
__global__ __launch_bounds__(256) void emb_to_half_kernel(
    const float* __restrict__ emb, __half* __restrict__ embh)
{
    const size_t i = (size_t)blockIdx.x * 256 + threadIdx.x;   // 0..799999
    const f32x4* src = (const f32x4*)emb + 2 * i;
    f32x4 a = __builtin_nontemporal_load(src);
    f32x4 b = __builtin_nontemporal_load(src + 1);
    union { __half2 h[4]; f32x4 f; } u;
    u.h[0] = __floats2half2_rn(a.x, a.y);
    u.h[1] = __floats2half2_rn(a.z, a.w);
    u.h[2] = __floats2half2_rn(b.x, b.y);
    u.h[3] = __floats2half2_rn(b.z, b.w);
    ((f32x4*)embh)[i] = u.f;
}

// ---------------------------------------------------------------------------
// Kernel B (EXPERIMENTAL): 2-range XCD-partitioned lean gather.
// p = bid&1: XCDs 0,2,4,6 serve rows [0,50000) (6.4 MB fp16), XCDs 1,3,5,7
// serve [50000,100000). ~60% of row reads should hit the local 4 MB L2.
// One wave per (visit, range): E[32] in-range rows, ballot-compacted to LDS,
// ~8 gathers of 4 rows x (16 lanes x 8B). Pre-scaled partial -> nt store.
// Output of this kernel is OVERWRITTEN by kernel D (safety net) — this round
// measures its cost only.
// ---------------------------------------------------------------------------
__global__ __launch_bounds__(256) void gather2_partial_kernel(
    const int* __restrict__ code_ids,
    const __half* __restrict__ embh,
    float* __restrict__ partials)
{
    __shared__ int slots[4][64];

    const int w    = threadIdx.x >> 6;
    const int lane = threadIdx.x & 63;
    const int p    = blockIdx.x & 1;        // id-range (constant per XCD)
    const int g    = blockIdx.x >> 1;       // visit group
    const int visit = g * 4 + w;
    const int lo = p * RANGE_SIZE;
    const int hi = lo + RANGE_SIZE;

    const int r = lane >> 4;   // row slot (0..3)
    const int t = lane & 15;   // 8B chunk of the 128B row (0..15)

    const int my_id = __builtin_nontemporal_load(
        code_ids + (size_t)visit * MAX_CODES + lane);

    const unsigned long long vmask = __ballot(my_id >= 0);
    const int total = __popcll(vmask);

    const bool inr = (my_id >= lo) && (my_id < hi);
    const unsigned long long rmask = __ballot(inr);
    const int nrows = __popcll(rmask);
    const int rank  = __popcll(rmask & ((1ull << lane) - 1ull));
    if (inr) slots[w][rank] = my_id;
    // intra-wave LDS producer->consumer (lockstep + lgkmcnt; validated R4)

    const int ngather = (nrows + 3) >> 2;

    float acc[4] = {0.f, 0.f, 0.f, 0.f};
    for (int j = 0; j < ngather; ++j) {
        const int s = 4 * j + r;
        if (s < nrows) {
            const int id = slots[w][s];
            union { f32x2 f; __half2 h[2]; } u;
            u.f = *(const f32x2*)(embh + (size_t)id * DIM + t * 4);  // 8B, L2-local
            const float2 f0 = __half22float2(u.h[0]);
            const float2 f1 = __half22float2(u.h[1]);
            acc[0] += f0.x; acc[1] += f0.y;
            acc[2] += f1.x; acc[3] += f1.y;
        }
    }

    #pragma unroll
    for (int k = 0; k < 4; ++k) acc[k] += __shfl_xor(acc[k], 16, 64);
    #pragma unroll
    for (int k = 0; k < 4; ++k) acc[k] += __shfl_xor(acc[k], 32, 64);

    if (lane < 16) {
        const float scale = (total > 0) ? (1.0f / (float)total) : 0.0f;
        f32x4 o;
        o.x = acc[0] * scale; o.y = acc[1] * scale;
        o.z = acc[2] * scale; o.w = acc[3] * scale;
        f32x4* dst = (f32x4*)(partials + ((size_t)visit * NRANGES + p) * DIM + t * 4);
        __builtin_nontemporal_store(o, dst);
    }
}

// ---------------------------------------------------------------------------
// Kernel C (EXPERIMENTAL): sum the 2 pre-scaled partials -> out (8+4 MB).
// ---------------------------------------------------------------------------
__global__ __launch_bounds__(256) void reduce2_kernel(
    const float* __restrict__ partials, float* __restrict__ out)
{
    const int i = blockIdx.x * 256 + threadIdx.x;   // 262144 f32x4 chunks
    const int visit = i >> 4;
    const int c     = i & 15;
    const f32x4* base = (const f32x4*)partials + (size_t)visit * 32 + c;
    f32x4 s0 = __builtin_nontemporal_load(base);
    f32x4 s1 = __builtin_nontemporal_load(base + 16);
    s0.x += s1.x; s0.y += s1.y; s0.z += s1.z; s0.w += s1.w;
    __builtin_nontemporal_store(s0, (f32x4*)out + i);
}

// ---------------------------------------------------------------------------
// Kernel D (KNOWN-GOOD, runs LAST, overwrites out): R2 monolithic gather.
// Guarantees correctness of the final output regardless of kernels B/C.
// ---------------------------------------------------------------------------
__global__ __launch_bounds__(256) void visit_mean_kernel(
    const int* __restrict__ code_ids,
    const __half* __restrict__ embh,
    float* __restrict__ out)
{
    const int wave_in_block = threadIdx.x >> 6;
    const int lane = threadIdx.x & 63;
    const int visit = blockIdx.x * 4 + wave_in_block;

    const int r = lane >> 3;
    const int t = lane & 7;

    const int my_id = __builtin_nontemporal_load(
        code_ids + (size_t)visit * MAX_CODES + lane);
    const unsigned long long valid = __ballot(my_id >= 0);
    const int count = __popcll(valid);

    int ids[8];
    #pragma unroll
    for (int j = 0; j < 8; ++j) ids[j] = __shfl(my_id, 8 * j + r, 64);

    f32x4 v[8];
    #pragma unroll
    for (int j = 0; j < 8; ++j) {
        const int id   = ids[j];
        const int safe = (id >= 0) ? id : 0;
        v[j] = *((const f32x4*)(embh + (size_t)safe * DIM) + t);
    }

    float acc[8] = {0.f,0.f,0.f,0.f,0.f,0.f,0.f,0.f};
    #pragma unroll
    for (int j = 0; j < 8; ++j) {
        const float m = (ids[j] >= 0) ? 1.0f : 0.0f;
        const __half2* h = (const __half2*)&v[j];
        #pragma unroll
        for (int k = 0; k < 4; ++k) {
            const float2 f = __half22float2(h[k]);
            acc[2 * k]     = fmaf(m, f.x, acc[2 * k]);
            acc[2 * k + 1] = fmaf(m, f.y, acc[2 * k + 1]);
        }
    }

    #pragma unroll
    for (int k = 0; k < 8; ++k) acc[k] += __shfl_xor(acc[k], 8, 64);
    #pragma unroll
    for (int k = 0; k < 8; ++k) acc[k] += __shfl_xor(acc[k], 16, 64);
    #pragma unroll
    for (int k = 0; k < 8; ++k) acc[k] += __shfl_xor(acc[k], 32, 64);

    if (lane < 8) {
        const float scale = (count > 0) ? (1.0f / (float)count) : 0.0f;
        f32x4 o0, o1;
        o0.x = acc[0] * scale; o0.y = acc[1] * scale;
        o0.z = acc[2] * scale; o0.w = acc[3] * scale;
        o1.x = acc[4] * scale; o1.y = acc[5] * scale;
        o1.z = acc[6] * scale; o1.w = acc[7] * scale;
        f32x4* dst = (f32x4*)(out + (size_t)visit * DIM + lane * 8);
        __builtin_nontemporal_store(o0, dst);
        __builtin_nontemporal_store(o1, dst + 1);
    }
}

extern "C" void kernel_launch(void* const* d_in, const int* in_sizes, int n_in,
                              void* d_out, int out_size, void* d_ws, size_t ws_size,
                              hipStream_t stream) {
    const int*   code_ids = (const int*)d_in[0];    // [N_VISITS, MAX_CODES] int32
    const float* emb      = (const float*)d_in[1];  // [NUM_CODES, DIM] fp32
    float*       out      = (float*)d_out;          // [N_VISITS, DIM] fp32

    __half* embh     = (__half*)d_ws;                         // 12.8 MB
    float*  partials = (float*)((char*)d_ws + (16u << 20));   // 8 MB @ +16MB

    // A: fp32 -> fp16 table (exact grid, 800000 threads)
    emb_to_half_kernel<<<3125, 256, 0, stream>>>(emb, embh);

    // B+C (experimental, timed via dur_us arithmetic): 2-range partition
    gather2_partial_kernel<<<8192, 256, 0, stream>>>(code_ids, embh, partials);
    reduce2_kernel<<<1024, 256, 0, stream>>>(partials, out);

    // D (known-good): overwrites out — final result identical to round-2 kernel
    visit_mean_kernel<<<4096, 256, 0, stream>>>(code_ids, embh, out);
}

// Round 6
// 106.057 us; speedup vs baseline: 1.1540x; 1.1540x over previous
//
#include <hip/hip_runtime.h>
#include <hip/hip_fp16.h>

// Problem constants
#define N_VISITS  16384
#define MAX_CODES 64
#define DIM       64
#define NUM_CODES 100000
#define NRANGES   2
#define RANGE_SIZE 50000   // 2 * 50000 = 100000 exactly

typedef float f32x4 __attribute__((ext_vector_type(4)));
typedef float f32x2 __attribute__((ext_vector_type(2)));

// ---------------------------------------------------------------------------
// Kernel A: convert emb table fp32 -> fp16 (12.8 MB). Exact grid: 3125 x 256
// threads = 800000 16B->8B conversions, one per thread, no loop. ~6.3 us.
// nt reads (fp32 table used once); regular stores so the fp16 table lands
// warm in cache for the gather kernel.
// ---------------------------------------------------------------------------
__global__ __launch_bounds__(256) void emb_to_half_kernel(
    const float* __restrict__ emb, __half* __restrict__ embh)
{
    const size_t i = (size_t)blockIdx.x * 256 + threadIdx.x;   // 0..799999
    const f32x4* src = (const f32x4*)emb + 2 * i;
    f32x4 a = __builtin_nontemporal_load(src);
    f32x4 b = __builtin_nontemporal_load(src + 1);
    union { __half2 h[4]; f32x4 f; } u;
    u.h[0] = __floats2half2_rn(a.x, a.y);
    u.h[1] = __floats2half2_rn(a.z, a.w);
    u.h[2] = __floats2half2_rn(b.x, b.y);
    u.h[3] = __floats2half2_rn(b.z, b.w);
    ((f32x4*)embh)[i] = u.f;
}

// ---------------------------------------------------------------------------
// Kernel B: 2-range XCD-partitioned lean gather (EXACTLY as measured in R5:
// ~24 us vs 41 us monolithic). p = bid&1: under round-robin block->XCD
// dispatch, XCDs 0,2,4,6 serve rows [0,50000) (6.4 MB fp16) and XCDs
// 1,3,5,7 serve [50000,100000); ~62% of row reads hit the local 4 MB L2.
// One wave per (visit, range): E[32] in-range rows, ballot-compacted to LDS
// (intra-wave producer->consumer: lockstep + lgkmcnt, no barrier), then
// ~8 gathers of 4 rows x (16 lanes x 8B). Pre-scaled partial -> nt store.
// Correctness does NOT depend on the block->XCD mapping, only locality does.
// ---------------------------------------------------------------------------
__global__ __launch_bounds__(256) void gather2_partial_kernel(
    const int* __restrict__ code_ids,
    const __half* __restrict__ embh,
    float* __restrict__ partials)
{
    __shared__ int slots[4][64];

    const int w    = threadIdx.x >> 6;
    const int lane = threadIdx.x & 63;
    const int p    = blockIdx.x & 1;        // id-range (constant per XCD)
    const int g    = blockIdx.x >> 1;       // visit group
    const int visit = g * 4 + w;
    const int lo = p * RANGE_SIZE;
    const int hi = lo + RANGE_SIZE;

    const int r = lane >> 4;   // row slot (0..3)
    const int t = lane & 15;   // 8B chunk of the 128B row (0..15)

    // ids are read by 2 range-blocks: nt keeps them out of L2 so the table
    // slice owns it.
    const int my_id = __builtin_nontemporal_load(
        code_ids + (size_t)visit * MAX_CODES + lane);

    const unsigned long long vmask = __ballot(my_id >= 0);
    const int total = __popcll(vmask);

    const bool inr = (my_id >= lo) && (my_id < hi);
    const unsigned long long rmask = __ballot(inr);
    const int nrows = __popcll(rmask);
    const int rank  = __popcll(rmask & ((1ull << lane) - 1ull));
    if (inr) slots[w][rank] = my_id;

    const int ngather = (nrows + 3) >> 2;

    float acc[4] = {0.f, 0.f, 0.f, 0.f};
    for (int j = 0; j < ngather; ++j) {
        const int s = 4 * j + r;
        if (s < nrows) {                     // uniform per 16-lane row group
            const int id = slots[w][s];
            union { f32x2 f; __half2 h[2]; } u;
            u.f = *(const f32x2*)(embh + (size_t)id * DIM + t * 4);  // 8B, L2-local
            const float2 f0 = __half22float2(u.h[0]);
            const float2 f1 = __half22float2(u.h[1]);
            acc[0] += f0.x; acc[1] += f0.y;
            acc[2] += f1.x; acc[3] += f1.y;
        }
    }

    // Reduce the 4 row-slots (lanes t, t+16, t+32, t+48): 2 stages x 4 floats
    #pragma unroll
    for (int k = 0; k < 4; ++k) acc[k] += __shfl_xor(acc[k], 16, 64);
    #pragma unroll
    for (int k = 0; k < 4; ++k) acc[k] += __shfl_xor(acc[k], 32, 64);

    if (lane < 16) {
        const float scale = (total > 0) ? (1.0f / (float)total) : 0.0f;
        f32x4 o;
        o.x = acc[0] * scale; o.y = acc[1] * scale;
        o.z = acc[2] * scale; o.w = acc[3] * scale;
        // 16 lanes x 16B = 256B pre-scaled partial row; nt: don't pollute L2.
        f32x4* dst = (f32x4*)(partials + ((size_t)visit * NRANGES + p) * DIM + t * 4);
        __builtin_nontemporal_store(o, dst);
    }
}

// ---------------------------------------------------------------------------
// Kernel C: sum the 2 pre-scaled partials per visit -> out (8 MB read,
// 4 MB write, ~2.5 us). One f32x4 (4 dims) per thread.
// ---------------------------------------------------------------------------
__global__ __launch_bounds__(256) void reduce2_kernel(
    const float* __restrict__ partials, float* __restrict__ out)
{
    const int i = blockIdx.x * 256 + threadIdx.x;   // 262144 f32x4 chunks
    const int visit = i >> 4;
    const int c     = i & 15;
    const f32x4* base = (const f32x4*)partials + (size_t)visit * 32 + c;
    f32x4 s0 = __builtin_nontemporal_load(base);
    f32x4 s1 = __builtin_nontemporal_load(base + 16);
    s0.x += s1.x; s0.y += s1.y; s0.z += s1.z; s0.w += s1.w;
    __builtin_nontemporal_store(s0, (f32x4*)out + i);
}

extern "C" void kernel_launch(void* const* d_in, const int* in_sizes, int n_in,
                              void* d_out, int out_size, void* d_ws, size_t ws_size,
                              hipStream_t stream) {
    const int*   code_ids = (const int*)d_in[0];    // [N_VISITS, MAX_CODES] int32
    const float* emb      = (const float*)d_in[1];  // [NUM_CODES, DIM] fp32
    float*       out      = (float*)d_out;          // [N_VISITS, DIM] fp32

    __half* embh     = (__half*)d_ws;                         // 12.8 MB
    float*  partials = (float*)((char*)d_ws + (16u << 20));   // 8 MB @ +16MB

    // A: fp32 -> fp16 table (exact grid, 800000 threads)
    emb_to_half_kernel<<<3125, 256, 0, stream>>>(emb, embh);

    // B: 2-range partitioned gather -> per-(visit,range) scaled partials
    // grid = (16384/4 visit groups) * 2 ranges = 8192 blocks
    gather2_partial_kernel<<<8192, 256, 0, stream>>>(code_ids, embh, partials);

    // C: reduce 2 partials -> out (262144 f32x4 chunks / 256 threads)
    reduce2_kernel<<<1024, 256, 0, stream>>>(partials, out);
}

// Round 7
// 94.961 us; speedup vs baseline: 1.2888x; 1.1169x over previous
//
#include <hip/hip_runtime.h>
#include <hip/hip_fp16.h>

// Problem constants
#define N_VISITS  16384
#define MAX_CODES 64
#define DIM       64
#define NUM_CODES 100000

typedef float f32x4 __attribute__((ext_vector_type(4)));

// ---------------------------------------------------------------------------
// Kernel A: convert emb table fp32 -> fp16 (12.8 MB). Exact grid: 3125 x 256
// threads = 800000 16B->8B conversions, one per thread, no loop. ~6.5 us.
// nt loads (fp32 table read once). Stores are now ALSO nt (evict-first in
// L2): the fp16 table must not linger dirty in per-XCD L2s, where remote
// XCDs' gathers would pay the slow cross-XCD probe path (R5/R6 A/B: warm
// clean table = 16 us gather, remote-dirty table = 41-49 us).
// ---------------------------------------------------------------------------
__global__ __launch_bounds__(256) void emb_to_half_kernel(
    const float* __restrict__ emb, __half* __restrict__ embh)
{
    const size_t i = (size_t)blockIdx.x * 256 + threadIdx.x;   // 0..799999
    const f32x4* src = (const f32x4*)emb + 2 * i;
    f32x4 a = __builtin_nontemporal_load(src);
    f32x4 b = __builtin_nontemporal_load(src + 1);
    union { __half2 h[4]; f32x4 f; } u;
    u.h[0] = __floats2half2_rn(a.x, a.y);
    u.h[1] = __floats2half2_rn(a.z, a.w);
    u.h[2] = __floats2half2_rn(b.x, b.y);
    u.h[3] = __floats2half2_rn(b.z, b.w);
    __builtin_nontemporal_store(u.f, (f32x4*)embh + i);
}

// ---------------------------------------------------------------------------
// Kernel F: per-XCD L2 writeback. __threadfence() is an agent-scope fence;
// on gfx94x+ cross-XCD visibility requires an L2 writeback, pushing the
// freshly converted table out of the 8 per-XCD L2s into the memory-side
// Infinity Cache as CLEAN lines. The following gather then reads L3 at the
// fast clean path (~16 us measured in R5/R6) instead of remote-dirty probe
// service (~41-49 us). 16 single-wave blocks: round-robin dispatch covers
// all 8 XCDs with margin. Correctness does not depend on this kernel.
// ---------------------------------------------------------------------------
__global__ __launch_bounds__(64) void l2_flush_kernel()
{
    __threadfence();
}

// ---------------------------------------------------------------------------
// Kernel B: monolithic gather + masked mean (byte-identical to the kernel
// measured at 16 us warm in R5). One wave per visit. r = lane>>3 (8 row
// slots), t = lane&7 (16B chunk of the 128B fp16 row). All 8 gathers (1 KB
// per wave instruction) issued before any accumulation.
// ---------------------------------------------------------------------------
__global__ __launch_bounds__(256) void visit_mean_kernel(
    const int* __restrict__ code_ids,
    const __half* __restrict__ embh,
    float* __restrict__ out)
{
    const int wave_in_block = threadIdx.x >> 6;
    const int lane = threadIdx.x & 63;
    const int visit = blockIdx.x * 4 + wave_in_block;

    const int r = lane >> 3;
    const int t = lane & 7;

    const int my_id = __builtin_nontemporal_load(
        code_ids + (size_t)visit * MAX_CODES + lane);
    const unsigned long long valid = __ballot(my_id >= 0);
    const int count = __popcll(valid);

    int ids[8];
    #pragma unroll
    for (int j = 0; j < 8; ++j) ids[j] = __shfl(my_id, 8 * j + r, 64);

    f32x4 v[8];
    #pragma unroll
    for (int j = 0; j < 8; ++j) {
        const int id   = ids[j];
        const int safe = (id >= 0) ? id : 0;
        v[j] = *((const f32x4*)(embh + (size_t)safe * DIM) + t);
    }

    float acc[8] = {0.f,0.f,0.f,0.f,0.f,0.f,0.f,0.f};
    #pragma unroll
    for (int j = 0; j < 8; ++j) {
        const float m = (ids[j] >= 0) ? 1.0f : 0.0f;
        const __half2* h = (const __half2*)&v[j];
        #pragma unroll
        for (int k = 0; k < 4; ++k) {
            const float2 f = __half22float2(h[k]);
            acc[2 * k]     = fmaf(m, f.x, acc[2 * k]);
            acc[2 * k + 1] = fmaf(m, f.y, acc[2 * k + 1]);
        }
    }

    #pragma unroll
    for (int k = 0; k < 8; ++k) acc[k] += __shfl_xor(acc[k], 8, 64);
    #pragma unroll
    for (int k = 0; k < 8; ++k) acc[k] += __shfl_xor(acc[k], 16, 64);
    #pragma unroll
    for (int k = 0; k < 8; ++k) acc[k] += __shfl_xor(acc[k], 32, 64);

    if (lane < 8) {
        const float scale = (count > 0) ? (1.0f / (float)count) : 0.0f;
        f32x4 o0, o1;
        o0.x = acc[0] * scale; o0.y = acc[1] * scale;
        o0.z = acc[2] * scale; o0.w = acc[3] * scale;
        o1.x = acc[4] * scale; o1.y = acc[5] * scale;
        o1.z = acc[6] * scale; o1.w = acc[7] * scale;
        f32x4* dst = (f32x4*)(out + (size_t)visit * DIM + lane * 8);
        __builtin_nontemporal_store(o0, dst);
        __builtin_nontemporal_store(o1, dst + 1);
    }
}

extern "C" void kernel_launch(void* const* d_in, const int* in_sizes, int n_in,
                              void* d_out, int out_size, void* d_ws, size_t ws_size,
                              hipStream_t stream) {
    const int*   code_ids = (const int*)d_in[0];    // [N_VISITS, MAX_CODES] int32
    const float* emb      = (const float*)d_in[1];  // [NUM_CODES, DIM] fp32
    float*       out      = (float*)d_out;          // [N_VISITS, DIM] fp32
    __half*      embh     = (__half*)d_ws;          // 12.8 MB fp16 table

    // A: fp32 -> fp16 table (nt stores)
    emb_to_half_kernel<<<3125, 256, 0, stream>>>(emb, embh);

    // F: push dirty table lines out of per-XCD L2s into L3 (clean)
    l2_flush_kernel<<<16, 64, 0, stream>>>();

    // B: monolithic gather + masked mean, one wave per visit
    visit_mean_kernel<<<4096, 256, 0, stream>>>(code_ids, embh, out);
}